// Round 5
// baseline (312.308 us; speedup 1.0000x reference)
//
#include <hip/hip_runtime.h>
#include <hip/hip_bf16.h>

typedef __attribute__((ext_vector_type(8))) short short8;
typedef __attribute__((ext_vector_type(4))) float f32x4;

#define DEV __device__ __forceinline__

DEV float bf2f(unsigned short u) {
    union { unsigned int i; float f; } v;
    v.i = ((unsigned int)u) << 16;
    return v.f;
}
DEV unsigned short f2bf(float f) {
    union { float f; unsigned int i; } v; v.f = f;
    unsigned int r = v.i + 0x7FFFu + ((v.i >> 16) & 1u);
    return (unsigned short)(r >> 16);
}
DEV float sigmoidf_(float x) {
    return 1.0f / (1.0f + __expf(-x));
}

// ---------------------------------------------------------------------------
// 1. fp32 -> bf16 conversion for x and h
// ---------------------------------------------------------------------------
__global__ void conv_xh(const float* __restrict__ x, const float* __restrict__ h,
                        unsigned short* __restrict__ xw, unsigned short* __restrict__ hw,
                        int n)
{
    int i = (blockIdx.x * blockDim.x + threadIdx.x) * 8;
    const float* src; unsigned short* dst; int off;
    if (i < n) { src = x; dst = xw; off = i; }
    else       { src = h; dst = hw; off = i - n; }
    float4 a = *(const float4*)(src + off);
    float4 b = *(const float4*)(src + off + 4);
    union { uint4 v; unsigned short s[8]; } o;
    o.s[0]=f2bf(a.x); o.s[1]=f2bf(a.y); o.s[2]=f2bf(a.z); o.s[3]=f2bf(a.w);
    o.s[4]=f2bf(b.x); o.s[5]=f2bf(b.y); o.s[6]=f2bf(b.z); o.s[7]=f2bf(b.w);
    *(uint4*)(dst + off) = o.v;
}

// ---------------------------------------------------------------------------
// 2. transpose + convert weights into the two fused B^T layouts
// ---------------------------------------------------------------------------
__global__ void tconv(const float* __restrict__ Wiz, const float* __restrict__ Uhz,
                      const float* __restrict__ Wir, const float* __restrict__ Uhr,
                      const float* __restrict__ Win, const float* __restrict__ Uhn,
                      unsigned short* __restrict__ B1t, unsigned short* __restrict__ B3t)
{
    __shared__ float lds[32][33];
    const float* src; unsigned short* dst;
    switch (blockIdx.z) {
        case 0: src=Wiz; dst=B1t;                            break;
        case 1: src=Uhz; dst=B1t + 1024;                     break;
        case 2: src=Wir; dst=B1t + (size_t)1024*2048;        break;
        case 3: src=Uhr; dst=B1t + (size_t)1024*2048 + 1024; break;
        case 4: src=Win; dst=B3t;                            break;
        default: src=Uhn; dst=B3t + 1024;                    break;
    }
    int k0 = blockIdx.x * 32, n0 = blockIdx.y * 32;
    int tx = threadIdx.x & 31, ty = threadIdx.x >> 5;
    #pragma unroll
    for (int i = 0; i < 4; i++)
        lds[ty + 8*i][tx] = src[(size_t)(k0 + ty + 8*i)*1024 + n0 + tx];
    __syncthreads();
    #pragma unroll
    for (int i = 0; i < 4; i++)
        dst[(size_t)(n0 + ty + 8*i)*2048 + k0 + tx] = f2bf(lds[tx][ty + 8*i]);
}

// ---------------------------------------------------------------------------
// 3. GEMM1: 256x256 tile, BK=64, 8 waves (2Mx4N), 8-phase pipeline
//    (T3+T4 counted vmcnt + T5 setprio). A split: k<1024 -> A0, else A1
//    (row stride 1024 each). Bt [2048][2048]. Fused z/r epilogue.
//
//    LDS (dynamic, 128 KiB):
//      A: [2 buf][2 band][128 row'][64 k] bf16  (64 KiB), band b of M-tile =
//         rows {b*64..b*64+63} U {128+b*64..128+b*64+63}; row' = (m>>7)<<6 | (m&63)
//      B: same at +64 KiB; band b of N-tile = 32-row chunks with bit5==b;
//         row' = (n>>6)<<5 | (n&31)
//    Band = 16 KiB = one staging unit = 2 global_load_lds x 512 threads.
//    Schedule per iteration (tiles T=2i in buf0 p1-4, T+1 in buf1 p5-8),
//    quadrant (mh,nh) order (0,0),(0,1),(1,0),(1,1):
//      p1: ldsA(mh0)+ldsB(nh0), stage A[buf1,b1,T+1]
//      p2: ldsB(nh1),           stage A[buf0,b0,T+2]
//      p3: ldsA(mh1),           stage B[buf0,b0,T+2]
//      p4: -,                   stage B[buf0,b1,T+2], vmcnt(6)
//      p5-p8: mirror for buf1 with stages A[buf0,b1,T+2], A[buf1,b0,T+3],
//             B[buf1,b0,T+3], B[buf1,b1,T+3], vmcnt(6) at p8
//    Every stage targets a region whose last ds_read was a previous phase;
//    every tile is fully landed (vmcnt) before its first ds_read.
// ---------------------------------------------------------------------------
DEV void stage_band_A(char* smem, const unsigned short* A0, const unsigned short* A1,
                      int buf, int band, int ktile, int gm, int tid)
{
    const unsigned short* src = (ktile < 16) ? A0 : A1;
    int kofs = (ktile & 15) * 64;
    #pragma unroll
    for (int j = 0; j < 2; ++j) {
        int o  = tid * 16 + j * 8192;
        int rp = o >> 7;
        int k  = (o & 127) >> 1;
        int m  = ((rp >> 6) << 7) | (band << 6) | (rp & 63);
        const unsigned short* g = src + (size_t)(gm + m) * 1024 + kofs + k;
        __builtin_amdgcn_global_load_lds(
            (const __attribute__((address_space(1))) void*)g,
            (__attribute__((address_space(3))) void*)(smem + buf*32768 + band*16384 + o),
            16, 0, 0);
    }
}
DEV void stage_band_B(char* smem, const unsigned short* Bt,
                      int buf, int band, int ktile, int gn, int tid)
{
    #pragma unroll
    for (int j = 0; j < 2; ++j) {
        int o  = tid * 16 + j * 8192;
        int rp = o >> 7;
        int k  = (o & 127) >> 1;
        int n  = ((rp >> 5) << 6) | (band << 5) | (rp & 31);
        const unsigned short* g = Bt + (size_t)(gn + n) * 2048 + ktile * 64 + k;
        __builtin_amdgcn_global_load_lds(
            (const __attribute__((address_space(1))) void*)g,
            (__attribute__((address_space(3))) void*)(smem + 65536 + buf*32768 + band*16384 + o),
            16, 0, 0);
    }
}

#define LOAD_A(BUF,MH)                                                        \
    { _Pragma("unroll") for (int mi = 0; mi < 4; mi++)                        \
      { _Pragma("unroll") for (int ks = 0; ks < 2; ks++)                      \
        af[mi][ks] = *(const short8*)(smem + (BUF)*32768 + (MH)*16384         \
                                      + abase + mi*2048 + ks*64); } }
#define LOAD_B(BUF,NH,DST)                                                    \
    { _Pragma("unroll") for (int ni = 0; ni < 2; ni++)                        \
      { _Pragma("unroll") for (int ks = 0; ks < 2; ks++)                      \
        DST[ni][ks] = *(const short8*)(smem + (BUF)*32768 + (NH)*16384        \
                                       + bbase + ni*2048 + ks*64); } }
#define MM(MH,NH,BF)                                                          \
    { _Pragma("unroll") for (int mi = 0; mi < 4; mi++)                        \
      { _Pragma("unroll") for (int ni = 0; ni < 2; ni++)                      \
        { _Pragma("unroll") for (int ks = 0; ks < 2; ks++)                    \
          acc[(MH)*4+mi][(NH)*2+ni] = __builtin_amdgcn_mfma_f32_16x16x32_bf16(\
              af[mi][ks], BF[ni][ks], acc[(MH)*4+mi][(NH)*2+ni], 0, 0, 0); } } }
#define PH_MID(DO_VM)                                                         \
    if (DO_VM) asm volatile("s_waitcnt vmcnt(6)" ::: "memory");               \
    __builtin_amdgcn_s_barrier();                                             \
    asm volatile("s_waitcnt lgkmcnt(0)" ::: "memory");                        \
    __builtin_amdgcn_s_setprio(1);
#define PH_END                                                                \
    __builtin_amdgcn_s_setprio(0);                                            \
    __builtin_amdgcn_s_barrier();

__global__ __launch_bounds__(512, 2)
void gemm1_8ph(const unsigned short* __restrict__ A0,   // xw
               const unsigned short* __restrict__ A1,   // hw
               const unsigned short* __restrict__ Bt,   // B1t [2048][2048]
               const float* __restrict__ bz, const float* __restrict__ br,
               const float* __restrict__ hsrc,
               float* __restrict__ zbuf, unsigned short* __restrict__ rh)
{
    extern __shared__ char smem[];
    const int tid = threadIdx.x;

    // bijective XCD swizzle: 256 wgs, 8 XCDs, 32/XCD; each XCD owns one N-strip
    int wg = (blockIdx.x & 7) * 32 + (blockIdx.x >> 3);
    const int gm = (wg & 31) * 256;
    const int gn = (wg >> 5) * 256;

    const int w  = tid >> 6, l = tid & 63;
    const int wr = w >> 2, wc = w & 3;        // 2 x 4 waves
    const int lr = l & 15, lk = l >> 4;

    const int abase = wr*8192 + lr*128 + lk*16;          // A band byte base
    const int bbase = 65536 + wc*4096 + lr*128 + lk*16;  // B band byte base

    f32x4 acc[8][4] = {};
    short8 af[4][2], bf0[2][2], bf1[2][2];

    // prologue: tile0 (4 units) + tile1 (3 units); drain tile0
    stage_band_A(smem, A0, A1, 0, 0, 0, gm, tid);
    stage_band_A(smem, A0, A1, 0, 1, 0, gm, tid);
    stage_band_B(smem, Bt, 0, 0, 0, gn, tid);
    stage_band_B(smem, Bt, 0, 1, 0, gn, tid);
    stage_band_A(smem, A0, A1, 1, 0, 1, gm, tid);
    stage_band_B(smem, Bt, 1, 0, 1, gn, tid);
    stage_band_B(smem, Bt, 1, 1, 1, gn, tid);
    asm volatile("s_waitcnt vmcnt(6)" ::: "memory");
    __builtin_amdgcn_s_barrier();

    for (int it = 0; it < 16; ++it) {
        const int T  = 2 * it;
        const int t1 = (T+1 < 31) ? T+1 : 31;
        const int t2 = (T+2 < 31) ? T+2 : 31;
        const int t3 = (T+3 < 31) ? T+3 : 31;

        // ---- tile T in buf0 ----
        // p1 (mh0,nh0)
        LOAD_A(0,0); LOAD_B(0,0,bf0);
        stage_band_A(smem, A0, A1, 1, 1, t1, gm, tid);
        PH_MID(false); MM(0,0,bf0); PH_END;
        // p2 (mh0,nh1)
        LOAD_B(0,1,bf1);
        stage_band_A(smem, A0, A1, 0, 0, t2, gm, tid);
        PH_MID(false); MM(0,1,bf1); PH_END;
        // p3 (mh1,nh0)
        LOAD_A(0,1);
        stage_band_B(smem, Bt, 0, 0, t2, gn, tid);
        PH_MID(false); MM(1,0,bf0); PH_END;
        // p4 (mh1,nh1)
        stage_band_B(smem, Bt, 0, 1, t2, gn, tid);
        PH_MID(true); MM(1,1,bf1); PH_END;

        // ---- tile T+1 in buf1 ----
        // p5 (mh0,nh0)
        LOAD_A(1,0); LOAD_B(1,0,bf0);
        stage_band_A(smem, A0, A1, 0, 1, t2, gm, tid);
        PH_MID(false); MM(0,0,bf0); PH_END;
        // p6 (mh0,nh1)
        LOAD_B(1,1,bf1);
        stage_band_A(smem, A0, A1, 1, 0, t3, gm, tid);
        PH_MID(false); MM(0,1,bf1); PH_END;
        // p7 (mh1,nh0)
        LOAD_A(1,1);
        stage_band_B(smem, Bt, 1, 0, t3, gn, tid);
        PH_MID(false); MM(1,0,bf0); PH_END;
        // p8 (mh1,nh1)
        stage_band_B(smem, Bt, 1, 1, t3, gn, tid);
        PH_MID(true); MM(1,1,bf1); PH_END;
    }

    // epilogue: C/D layout col=lane&15, row=(lane>>4)*4+reg (m89/m91)
    #pragma unroll
    for (int Mi = 0; Mi < 8; Mi++) {
        #pragma unroll
        for (int j = 0; j < 4; j++) {
            int row = gm + wr*128 + Mi*16 + lk*4 + j;
            #pragma unroll
            for (int Ni = 0; Ni < 4; Ni++) {
                int col = gn + wc*64 + Ni*16 + lr;
                float v = acc[Mi][Ni][j];
                if (col < 1024) {
                    zbuf[(size_t)row*1024 + col] = sigmoidf_(v + bz[col]);
                } else {
                    int c = col - 1024;
                    float rv = sigmoidf_(v + br[c]);
                    rh[(size_t)row*1024 + c] = f2bf(rv * hsrc[(size_t)row*1024 + c]);
                }
            }
        }
    }
}

// ---------------------------------------------------------------------------
// 4. GEMM2 (verified m97 structure): [x|rh] @ [[Win],[Uhn]] + GRU epilogue
// ---------------------------------------------------------------------------
__global__ __launch_bounds__(256, 2)
void gemm2_m97(const unsigned short* __restrict__ A0,
               const unsigned short* __restrict__ A1,
               const unsigned short* __restrict__ Bt,
               const float* __restrict__ bn,
               const float* __restrict__ hsrc,
               const float* __restrict__ zbuf,
               float* __restrict__ out)
{
    __shared__ unsigned short lA[128*32];
    __shared__ unsigned short lB[128*32];
    const int tid = threadIdx.x;
    const int gm = blockIdx.x * 128, gn = blockIdx.y * 128;

    const int w  = tid >> 6, l = tid & 63;
    const int wm = (w >> 1) * 64, wn = (w & 1) * 64;
    const int lr = l & 15, lk = l >> 4;

    f32x4 acc[4][4] = {};

    const int srow = tid >> 2;
    const int scol = (tid & 3) * 8;
    char* lAp = (char*)lA + tid * 16;
    char* lBp = (char*)lB + tid * 16;

    for (int kt = 0; kt < 2048; kt += 32) {
        const unsigned short* Ab = (kt < 1024 ? A0 : A1)
                                 + (size_t)(gm + srow) * 1024 + (kt & 1023) + scol;
        const unsigned short* Bb = Bt + (size_t)(gn + srow) * 2048 + kt + scol;
        __syncthreads();
        __builtin_amdgcn_global_load_lds(
            (const __attribute__((address_space(1))) void*)Ab,
            (__attribute__((address_space(3))) void*)lAp, 16, 0, 0);
        __builtin_amdgcn_global_load_lds(
            (const __attribute__((address_space(1))) void*)(Ab + (size_t)64*1024),
            (__attribute__((address_space(3))) void*)(lAp + 4096), 16, 0, 0);
        __builtin_amdgcn_global_load_lds(
            (const __attribute__((address_space(1))) void*)Bb,
            (__attribute__((address_space(3))) void*)lBp, 16, 0, 0);
        __builtin_amdgcn_global_load_lds(
            (const __attribute__((address_space(1))) void*)(Bb + (size_t)64*2048),
            (__attribute__((address_space(3))) void*)(lBp + 4096), 16, 0, 0);
        __syncthreads();

        short8 af[4], bfr[4];
        #pragma unroll
        for (int mi = 0; mi < 4; mi++)
            af[mi] = *(const short8*)&lA[(wm + mi*16 + lr)*32 + lk*8];
        #pragma unroll
        for (int ni = 0; ni < 4; ni++)
            bfr[ni] = *(const short8*)&lB[(wn + ni*16 + lr)*32 + lk*8];
        #pragma unroll
        for (int mi = 0; mi < 4; mi++)
            #pragma unroll
            for (int ni = 0; ni < 4; ni++)
                acc[mi][ni] = __builtin_amdgcn_mfma_f32_16x16x32_bf16(
                    af[mi], bfr[ni], acc[mi][ni], 0, 0, 0);
    }

    #pragma unroll
    for (int mi = 0; mi < 4; mi++) {
        #pragma unroll
        for (int j = 0; j < 4; j++) {
            int row = gm + wm + mi*16 + lk*4 + j;
            #pragma unroll
            for (int ni = 0; ni < 4; ni++) {
                int col = gn + wn + ni*16 + lr;
                float nv = sigmoidf_(acc[mi][ni][j] + bn[col]);
                float zv = zbuf[(size_t)row*1024 + col];
                float hv = hsrc[(size_t)row*1024 + col];
                out[(size_t)row*1024 + col] = (1.0f - zv)*hv + zv*nv;
            }
        }
    }
}

// ---------------------------------------------------------------------------
extern "C" void kernel_launch(void* const* d_in, const int* in_sizes, int n_in,
                              void* d_out, int out_size, void* d_ws, size_t ws_size,
                              hipStream_t stream)
{
    const float* x   = (const float*)d_in[0];
    const float* h   = (const float*)d_in[1];
    const float* Wiz = (const float*)d_in[2];
    const float* Uhz = (const float*)d_in[3];
    const float* bz  = (const float*)d_in[4];
    const float* Wir = (const float*)d_in[5];
    const float* Uhr = (const float*)d_in[6];
    const float* br  = (const float*)d_in[7];
    const float* Win = (const float*)d_in[8];
    const float* Uhn = (const float*)d_in[9];
    const float* bn  = (const float*)d_in[10];
    float* out = (float*)d_out;

    char* ws = (char*)d_ws;
    const size_t MB = 1024ull * 1024ull;
    unsigned short* xw   = (unsigned short*)(ws + 0);        // 16 MB [8192][1024]
    unsigned short* hw   = (unsigned short*)(ws + 16*MB);    // 16 MB [8192][1024]
    unsigned short* B1t  = (unsigned short*)(ws + 32*MB);    //  8 MB [2048][2048]
    unsigned short* B3t  = (unsigned short*)(ws + 40*MB);    //  4 MB [1024][2048]
    float*          zbuf = (float*)(ws + 44*MB);             // 32 MB [8192][1024]
    unsigned short* rh   = (unsigned short*)(ws + 76*MB);    // 16 MB -> total 92 MB

    const int B = 8192, H = 1024;

    // allow 128 KiB dynamic LDS for the 8-phase GEMM (idempotent, graph-safe)
    (void)hipFuncSetAttribute((const void*)gemm1_8ph,
                              hipFuncAttributeMaxDynamicSharedMemorySize, 131072);

    conv_xh<<<dim3(2*B*H/8/256), dim3(256), 0, stream>>>(x, h, xw, hw, B*H);

    tconv<<<dim3(32, 32, 6), dim3(256), 0, stream>>>(
        Wiz, Uhz, Wir, Uhr, Win, Uhn, B1t, B3t);

    // [x|h] @ [[Wiz|Wir],[Uhz|Uhr]] with fused z/r epilogue (8-phase 256^2)
    gemm1_8ph<<<dim3(256), dim3(512), 131072, stream>>>(
        xw, hw, B1t, bz, br, h, zbuf, rh);

    // [x|rh] @ [[Win],[Uhn]] with fused GRU output epilogue (m97 structure)
    gemm2_m97<<<dim3(64, 8), dim3(256), 0, stream>>>(
        xw, rh, B3t, bn, h, zbuf, out);
}

// Round 6
// 295.988 us; speedup vs baseline: 1.0551x; 1.0551x over previous
//
#include <hip/hip_runtime.h>
#include <hip/hip_bf16.h>

typedef __attribute__((ext_vector_type(8))) short short8;
typedef __attribute__((ext_vector_type(4))) float f32x4;

#define DEV __device__ __forceinline__

DEV float bf2f(unsigned short u) {
    union { unsigned int i; float f; } v;
    v.i = ((unsigned int)u) << 16;
    return v.f;
}
DEV unsigned short f2bf(float f) {
    union { float f; unsigned int i; } v; v.f = f;
    unsigned int r = v.i + 0x7FFFu + ((v.i >> 16) & 1u);
    return (unsigned short)(r >> 16);
}
DEV float sigmoidf_(float x) {
    return 1.0f / (1.0f + __expf(-x));
}

// ---------------------------------------------------------------------------
// 1. fp32 -> bf16 conversion for x and h
// ---------------------------------------------------------------------------
__global__ void conv_xh(const float* __restrict__ x, const float* __restrict__ h,
                        unsigned short* __restrict__ xw, unsigned short* __restrict__ hw,
                        int n)
{
    int i = (blockIdx.x * blockDim.x + threadIdx.x) * 8;
    const float* src; unsigned short* dst; int off;
    if (i < n) { src = x; dst = xw; off = i; }
    else       { src = h; dst = hw; off = i - n; }
    float4 a = *(const float4*)(src + off);
    float4 b = *(const float4*)(src + off + 4);
    union { uint4 v; unsigned short s[8]; } o;
    o.s[0]=f2bf(a.x); o.s[1]=f2bf(a.y); o.s[2]=f2bf(a.z); o.s[3]=f2bf(a.w);
    o.s[4]=f2bf(b.x); o.s[5]=f2bf(b.y); o.s[6]=f2bf(b.z); o.s[7]=f2bf(b.w);
    *(uint4*)(dst + off) = o.v;
}

// ---------------------------------------------------------------------------
// 2. transpose + convert weights into the two fused B^T layouts
// ---------------------------------------------------------------------------
__global__ void tconv(const float* __restrict__ Wiz, const float* __restrict__ Uhz,
                      const float* __restrict__ Wir, const float* __restrict__ Uhr,
                      const float* __restrict__ Win, const float* __restrict__ Uhn,
                      unsigned short* __restrict__ B1t, unsigned short* __restrict__ B3t)
{
    __shared__ float lds[32][33];
    const float* src; unsigned short* dst;
    switch (blockIdx.z) {
        case 0: src=Wiz; dst=B1t;                            break;
        case 1: src=Uhz; dst=B1t + 1024;                     break;
        case 2: src=Wir; dst=B1t + (size_t)1024*2048;        break;
        case 3: src=Uhr; dst=B1t + (size_t)1024*2048 + 1024; break;
        case 4: src=Win; dst=B3t;                            break;
        default: src=Uhn; dst=B3t + 1024;                    break;
    }
    int k0 = blockIdx.x * 32, n0 = blockIdx.y * 32;
    int tx = threadIdx.x & 31, ty = threadIdx.x >> 5;
    #pragma unroll
    for (int i = 0; i < 4; i++)
        lds[ty + 8*i][tx] = src[(size_t)(k0 + ty + 8*i)*1024 + n0 + tx];
    __syncthreads();
    #pragma unroll
    for (int i = 0; i < 4; i++)
        dst[(size_t)(n0 + ty + 8*i)*2048 + k0 + tx] = f2bf(lds[tx][ty + 8*i]);
}

// ---------------------------------------------------------------------------
// 3. GEMM1: 256x256 tile, BK=64, 8 waves (2Mx4N), 8-phase pipeline
//    (T3+T4 counted vmcnt + T5 setprio + T2 LDS XOR-swizzle + compact XCD map).
//
//    LDS bands as in R5; NEW: 16B-slot XOR swizzle, slot' = slot ^ (row&7).
//    gload_lds dest stays LINEAR; the *global source* k-offset carries the
//    inverse permutation; ds_read addresses carry the XOR (rule #21:
//    both-sides involution). Each ds_read_b128 now spreads 64 lanes evenly
//    over all 32 banks (8 lanes per 4-bank group).
//
//    XCD map: xcd = bid&7 owns an 8Mx4N block of 256^2 tiles -> per-k-step
//    working set 384 KB (L2-hot); A fetched <=2x, B <=4x => ~96 MB total.
// ---------------------------------------------------------------------------
DEV void stage_band_A(char* smem, const unsigned short* A0, const unsigned short* A1,
                      int buf, int band, int ktile, int gm, int tid)
{
    const unsigned short* src = (ktile < 16) ? A0 : A1;
    int kofs = (ktile & 15) * 64;
    #pragma unroll
    for (int j = 0; j < 2; ++j) {
        int o   = tid * 16 + j * 8192;
        int rp  = o >> 7;
        int kel = (((o >> 4) & 7) ^ (rp & 7)) << 3;   // inverse-swizzled k
        int m   = ((rp >> 6) << 7) | (band << 6) | (rp & 63);
        const unsigned short* g = src + (size_t)(gm + m) * 1024 + kofs + kel;
        __builtin_amdgcn_global_load_lds(
            (const __attribute__((address_space(1))) void*)g,
            (__attribute__((address_space(3))) void*)(smem + buf*32768 + band*16384 + o),
            16, 0, 0);
    }
}
DEV void stage_band_B(char* smem, const unsigned short* Bt,
                      int buf, int band, int ktile, int gn, int tid)
{
    #pragma unroll
    for (int j = 0; j < 2; ++j) {
        int o   = tid * 16 + j * 8192;
        int rp  = o >> 7;
        int kel = (((o >> 4) & 7) ^ (rp & 7)) << 3;
        int n   = ((rp >> 5) << 6) | (band << 5) | (rp & 31);
        const unsigned short* g = Bt + (size_t)(gn + n) * 2048 + ktile * 64 + kel;
        __builtin_amdgcn_global_load_lds(
            (const __attribute__((address_space(1))) void*)g,
            (__attribute__((address_space(3))) void*)(smem + 65536 + buf*32768 + band*16384 + o),
            16, 0, 0);
    }
}

#define LOAD_A(BUF,MH)                                                        \
    { _Pragma("unroll") for (int mi = 0; mi < 4; mi++)                        \
      { _Pragma("unroll") for (int ks = 0; ks < 2; ks++)                      \
        af[mi][ks] = *(const short8*)(smem + (BUF)*32768 + (MH)*16384         \
                        + arow + mi*2048 + ((((ks<<2)|lk)<<4) ^ aswz)); } }
#define LOAD_B(BUF,NH,DST)                                                    \
    { _Pragma("unroll") for (int ni = 0; ni < 2; ni++)                        \
      { _Pragma("unroll") for (int ks = 0; ks < 2; ks++)                      \
        DST[ni][ks] = *(const short8*)(smem + (BUF)*32768 + (NH)*16384        \
                        + brow + ni*2048 + ((((ks<<2)|lk)<<4) ^ aswz)); } }
#define MM(MH,NH,BF)                                                          \
    { _Pragma("unroll") for (int mi = 0; mi < 4; mi++)                        \
      { _Pragma("unroll") for (int ni = 0; ni < 2; ni++)                      \
        { _Pragma("unroll") for (int ks = 0; ks < 2; ks++)                    \
          acc[(MH)*4+mi][(NH)*2+ni] = __builtin_amdgcn_mfma_f32_16x16x32_bf16(\
              af[mi][ks], BF[ni][ks], acc[(MH)*4+mi][(NH)*2+ni], 0, 0, 0); } } }
#define PH_MID(DO_VM)                                                         \
    if (DO_VM) asm volatile("s_waitcnt vmcnt(6)" ::: "memory");               \
    __builtin_amdgcn_s_barrier();                                             \
    asm volatile("s_waitcnt lgkmcnt(0)" ::: "memory");                        \
    __builtin_amdgcn_s_setprio(1);
#define PH_END                                                                \
    __builtin_amdgcn_s_setprio(0);                                            \
    __builtin_amdgcn_s_barrier();

__global__ __launch_bounds__(512, 2)
void gemm1_8ph(const unsigned short* __restrict__ A0,   // xw
               const unsigned short* __restrict__ A1,   // hw
               const unsigned short* __restrict__ Bt,   // B1t [2048][2048]
               const float* __restrict__ bz, const float* __restrict__ br,
               const float* __restrict__ hsrc,
               float* __restrict__ zbuf, unsigned short* __restrict__ rh)
{
    extern __shared__ char smem[];
    const int tid = threadIdx.x;

    // compact per-XCD 8Mx4N tile block (dispatch round-robins bid across XCDs)
    const int bid = blockIdx.x;
    const int xcd = bid & 7, j = bid >> 3;               // j in 0..31
    const int mt  = (xcd >> 1) * 8 + (j >> 2);           // 0..31
    const int nt  = (xcd & 1) * 4 + (j & 3);             // 0..7
    const int gm = mt * 256, gn = nt * 256;

    const int w  = tid >> 6, l = tid & 63;
    const int wr = w >> 2, wc = w & 3;        // 2 x 4 waves
    const int lr = l & 15, lk = l >> 4;

    const int arow = wr*8192 + lr*128;                 // A row byte base
    const int brow = 65536 + wc*4096 + lr*128;         // B row byte base
    const int aswz = (lr & 7) << 4;                    // T2 XOR term

    f32x4 acc[8][4] = {};
    short8 af[4][2], bf0[2][2], bf1[2][2];

    // prologue: tile0 (4 units) + tile1 (3 units); drain tile0
    stage_band_A(smem, A0, A1, 0, 0, 0, gm, tid);
    stage_band_A(smem, A0, A1, 0, 1, 0, gm, tid);
    stage_band_B(smem, Bt, 0, 0, 0, gn, tid);
    stage_band_B(smem, Bt, 0, 1, 0, gn, tid);
    stage_band_A(smem, A0, A1, 1, 0, 1, gm, tid);
    stage_band_B(smem, Bt, 1, 0, 1, gn, tid);
    stage_band_B(smem, Bt, 1, 1, 1, gn, tid);
    asm volatile("s_waitcnt vmcnt(6)" ::: "memory");
    __builtin_amdgcn_s_barrier();

    for (int it = 0; it < 16; ++it) {
        const int T  = 2 * it;
        const int t1 = (T+1 < 31) ? T+1 : 31;
        const int t2 = (T+2 < 31) ? T+2 : 31;
        const int t3 = (T+3 < 31) ? T+3 : 31;

        // ---- tile T in buf0 ----
        LOAD_A(0,0); LOAD_B(0,0,bf0);
        stage_band_A(smem, A0, A1, 1, 1, t1, gm, tid);
        PH_MID(false); MM(0,0,bf0); PH_END;

        LOAD_B(0,1,bf1);
        stage_band_A(smem, A0, A1, 0, 0, t2, gm, tid);
        PH_MID(false); MM(0,1,bf1); PH_END;

        LOAD_A(0,1);
        stage_band_B(smem, Bt, 0, 0, t2, gn, tid);
        PH_MID(false); MM(1,0,bf0); PH_END;

        stage_band_B(smem, Bt, 0, 1, t2, gn, tid);
        PH_MID(true); MM(1,1,bf1); PH_END;

        // ---- tile T+1 in buf1 ----
        LOAD_A(1,0); LOAD_B(1,0,bf0);
        stage_band_A(smem, A0, A1, 0, 1, t2, gm, tid);
        PH_MID(false); MM(0,0,bf0); PH_END;

        LOAD_B(1,1,bf1);
        stage_band_A(smem, A0, A1, 1, 0, t3, gm, tid);
        PH_MID(false); MM(0,1,bf1); PH_END;

        LOAD_A(1,1);
        stage_band_B(smem, Bt, 1, 0, t3, gn, tid);
        PH_MID(false); MM(1,0,bf0); PH_END;

        stage_band_B(smem, Bt, 1, 1, t3, gn, tid);
        PH_MID(true); MM(1,1,bf1); PH_END;
    }

    // epilogue: C/D layout col=lane&15, row=(lane>>4)*4+reg (m89/m91)
    #pragma unroll
    for (int Mi = 0; Mi < 8; Mi++) {
        #pragma unroll
        for (int jj = 0; jj < 4; jj++) {
            int row = gm + wr*128 + Mi*16 + lk*4 + jj;
            #pragma unroll
            for (int Ni = 0; Ni < 4; Ni++) {
                int col = gn + wc*64 + Ni*16 + lr;
                float v = acc[Mi][Ni][jj];
                if (col < 1024) {
                    zbuf[(size_t)row*1024 + col] = sigmoidf_(v + bz[col]);
                } else {
                    int c = col - 1024;
                    float rv = sigmoidf_(v + br[c]);
                    rh[(size_t)row*1024 + c] = f2bf(rv * hsrc[(size_t)row*1024 + c]);
                }
            }
        }
    }
}

// ---------------------------------------------------------------------------
// 4. GEMM2 (verified m97 structure): [x|rh] @ [[Win],[Uhn]] + GRU epilogue
// ---------------------------------------------------------------------------
__global__ __launch_bounds__(256, 2)
void gemm2_m97(const unsigned short* __restrict__ A0,
               const unsigned short* __restrict__ A1,
               const unsigned short* __restrict__ Bt,
               const float* __restrict__ bn,
               const float* __restrict__ hsrc,
               const float* __restrict__ zbuf,
               float* __restrict__ out)
{
    __shared__ unsigned short lA[128*32];
    __shared__ unsigned short lB[128*32];
    const int tid = threadIdx.x;
    const int gm = blockIdx.x * 128, gn = blockIdx.y * 128;

    const int w  = tid >> 6, l = tid & 63;
    const int wm = (w >> 1) * 64, wn = (w & 1) * 64;
    const int lr = l & 15, lk = l >> 4;

    f32x4 acc[4][4] = {};

    const int srow = tid >> 2;
    const int scol = (tid & 3) * 8;
    char* lAp = (char*)lA + tid * 16;
    char* lBp = (char*)lB + tid * 16;

    for (int kt = 0; kt < 2048; kt += 32) {
        const unsigned short* Ab = (kt < 1024 ? A0 : A1)
                                 + (size_t)(gm + srow) * 1024 + (kt & 1023) + scol;
        const unsigned short* Bb = Bt + (size_t)(gn + srow) * 2048 + kt + scol;
        __syncthreads();
        __builtin_amdgcn_global_load_lds(
            (const __attribute__((address_space(1))) void*)Ab,
            (__attribute__((address_space(3))) void*)lAp, 16, 0, 0);
        __builtin_amdgcn_global_load_lds(
            (const __attribute__((address_space(1))) void*)(Ab + (size_t)64*1024),
            (__attribute__((address_space(3))) void*)(lAp + 4096), 16, 0, 0);
        __builtin_amdgcn_global_load_lds(
            (const __attribute__((address_space(1))) void*)Bb,
            (__attribute__((address_space(3))) void*)lBp, 16, 0, 0);
        __builtin_amdgcn_global_load_lds(
            (const __attribute__((address_space(1))) void*)(Bb + (size_t)64*2048),
            (__attribute__((address_space(3))) void*)(lBp + 4096), 16, 0, 0);
        __syncthreads();

        short8 af[4], bfr[4];
        #pragma unroll
        for (int mi = 0; mi < 4; mi++)
            af[mi] = *(const short8*)&lA[(wm + mi*16 + lr)*32 + lk*8];
        #pragma unroll
        for (int ni = 0; ni < 4; ni++)
            bfr[ni] = *(const short8*)&lB[(wn + ni*16 + lr)*32 + lk*8];
        #pragma unroll
        for (int mi = 0; mi < 4; mi++)
            #pragma unroll
            for (int ni = 0; ni < 4; ni++)
                acc[mi][ni] = __builtin_amdgcn_mfma_f32_16x16x32_bf16(
                    af[mi], bfr[ni], acc[mi][ni], 0, 0, 0);
    }

    #pragma unroll
    for (int mi = 0; mi < 4; mi++) {
        #pragma unroll
        for (int j = 0; j < 4; j++) {
            int row = gm + wm + mi*16 + lk*4 + j;
            #pragma unroll
            for (int ni = 0; ni < 4; ni++) {
                int col = gn + wn + ni*16 + lr;
                float nv = sigmoidf_(acc[mi][ni][j] + bn[col]);
                float zv = zbuf[(size_t)row*1024 + col];
                float hv = hsrc[(size_t)row*1024 + col];
                out[(size_t)row*1024 + col] = (1.0f - zv)*hv + zv*nv;
            }
        }
    }
}

// ---------------------------------------------------------------------------
extern "C" void kernel_launch(void* const* d_in, const int* in_sizes, int n_in,
                              void* d_out, int out_size, void* d_ws, size_t ws_size,
                              hipStream_t stream)
{
    const float* x   = (const float*)d_in[0];
    const float* h   = (const float*)d_in[1];
    const float* Wiz = (const float*)d_in[2];
    const float* Uhz = (const float*)d_in[3];
    const float* bz  = (const float*)d_in[4];
    const float* Wir = (const float*)d_in[5];
    const float* Uhr = (const float*)d_in[6];
    const float* br  = (const float*)d_in[7];
    const float* Win = (const float*)d_in[8];
    const float* Uhn = (const float*)d_in[9];
    const float* bn  = (const float*)d_in[10];
    float* out = (float*)d_out;

    char* ws = (char*)d_ws;
    const size_t MB = 1024ull * 1024ull;
    unsigned short* xw   = (unsigned short*)(ws + 0);        // 16 MB [8192][1024]
    unsigned short* hw   = (unsigned short*)(ws + 16*MB);    // 16 MB [8192][1024]
    unsigned short* B1t  = (unsigned short*)(ws + 32*MB);    //  8 MB [2048][2048]
    unsigned short* B3t  = (unsigned short*)(ws + 40*MB);    //  4 MB [1024][2048]
    float*          zbuf = (float*)(ws + 44*MB);             // 32 MB [8192][1024]
    unsigned short* rh   = (unsigned short*)(ws + 76*MB);    // 16 MB -> total 92 MB

    const int B = 8192, H = 1024;

    (void)hipFuncSetAttribute((const void*)gemm1_8ph,
                              hipFuncAttributeMaxDynamicSharedMemorySize, 131072);

    conv_xh<<<dim3(2*B*H/8/256), dim3(256), 0, stream>>>(x, h, xw, hw, B*H);

    tconv<<<dim3(32, 32, 6), dim3(256), 0, stream>>>(
        Wiz, Uhz, Wir, Uhr, Win, Uhn, B1t, B3t);

    // [x|h] @ [[Wiz|Wir],[Uhz|Uhr]] with fused z/r epilogue (8-phase 256^2)
    gemm1_8ph<<<dim3(256), dim3(512), 131072, stream>>>(
        xw, hw, B1t, bz, br, h, zbuf, rh);

    // [x|rh] @ [[Win],[Uhn]] with fused GRU output epilogue (m97 structure)
    gemm2_m97<<<dim3(64, 8), dim3(256), 0, stream>>>(
        xw, rh, B3t, bn, h, zbuf, out);
}